// Round 1
// 1452.483 us; speedup vs baseline: 1.1631x; 1.1631x over previous
//
#include <hip/hip_runtime.h>
#include <hip/hip_bf16.h>
#include <math.h>

typedef __hip_bfloat16 bf16;
typedef __attribute__((ext_vector_type(8))) short bf16x8;
typedef __attribute__((ext_vector_type(4))) float f32x4;

#define SEQ    1024
#define DMODEL 512
#define NTOK   2048
#define VOCAB  50257
#define NDFF   2048

// async global->LDS, 16B per lane; LDS dest = wave-uniform base + lane*16
__device__ __forceinline__ void async_cp16(const bf16* g, bf16* s) {
  __builtin_amdgcn_global_load_lds((const __attribute__((address_space(1))) void*)g,
                                   (__attribute__((address_space(3))) void*)s, 16, 0, 0);
}

// ---------------- generic NT GEMM: C = A @ B^T (+bias) (+epilogue) ----------
// A: [M,K] bf16 row-major (lda); B: [N,K] bf16 row-major (ldb)
// grid.x = M/128, grid.y = ceil(N/128), grid.z = batch (z = b*8+h decomposed)
// MODE 0: f32 store (bias optional)        MODE 1: bf16 store (bias optional)
// MODE 2: f32 = resid + bias + acc         MODE 3: bf16 = gelu_erf(acc + bias)
template<int MODE>
__global__ __launch_bounds__(256, 2) void gemm_nt(
    const bf16* A, long long sAb, long long sAh, int lda,
    const bf16* B, long long sBb, long long sBh, int ldb,
    const float* bias,
    void* Cptr, long long sCb, long long sCh, int ldc,
    const float* resid, int N, int K, int causal)
{
  if (causal && blockIdx.y > blockIdx.x) return;   // fully-masked causal tile
  int z = blockIdx.z;
  A += (size_t)(z >> 3) * sAb + (size_t)(z & 7) * sAh;
  B += (size_t)(z >> 3) * sBb + (size_t)(z & 7) * sBh;
  size_t coff = (size_t)(z >> 3) * sCb + (size_t)(z & 7) * sCh;

  __shared__ bf16 smA[128 * 32];
  __shared__ bf16 smB[128 * 32];

  const int tid  = threadIdx.x;
  const int wave = tid >> 6, lane = tid & 63;
  const int m0 = blockIdx.x * 128, n0 = blockIdx.y * 128;

  f32x4 acc[4][4];
#pragma unroll
  for (int r = 0; r < 4; ++r)
#pragma unroll
    for (int c = 0; c < 4; ++c) acc[r][c] = (f32x4){0.f, 0.f, 0.f, 0.f};

  // staging: tile = 128 rows x 32 bf16 (64B = 4 chunks of 16B per row)
  const int kc0 = (tid & 3) * 8;
  const int rA0 = m0 + (tid >> 2);
  const int rA1 = rA0 + 64;
  int rB0 = n0 + (tid >> 2);      if (rB0 > N - 1) rB0 = N - 1;
  int rB1 = n0 + 64 + (tid >> 2); if (rB1 > N - 1) rB1 = N - 1;
  const bf16* a0 = A + (size_t)rA0 * lda + kc0;
  const bf16* a1 = A + (size_t)rA1 * lda + kc0;
  const bf16* b0 = B + (size_t)rB0 * ldb + kc0;
  const bf16* b1 = B + (size_t)rB1 * ldb + kc0;
  bf16* sA0 = smA + wave * 512;
  bf16* sA1 = smA + 2048 + wave * 512;
  bf16* sB0 = smB + wave * 512;
  bf16* sB1 = smB + 2048 + wave * 512;

  const int fmA = (wave >> 1) * 64 + (lane & 15);
  const int fnB = (wave & 1) * 64 + (lane & 15);
  const int kq  = (lane >> 4) * 8;
  const short* sa = (const short*)smA;
  const short* sb = (const short*)smB;

  for (int k0 = 0; k0 < K; k0 += 32) {
    async_cp16(a0, sA0); async_cp16(a1, sA1);
    async_cp16(b0, sB0); async_cp16(b1, sB1);
    a0 += 32; a1 += 32; b0 += 32; b1 += 32;
    __syncthreads();
    bf16x8 af[4], bfr[4];
#pragma unroll
    for (int r = 0; r < 4; ++r) af[r]  = *(const bf16x8*)(sa + (fmA + r * 16) * 32 + kq);
#pragma unroll
    for (int c = 0; c < 4; ++c) bfr[c] = *(const bf16x8*)(sb + (fnB + c * 16) * 32 + kq);
#pragma unroll
    for (int r = 0; r < 4; ++r)
#pragma unroll
      for (int c = 0; c < 4; ++c)
        acc[r][c] = __builtin_amdgcn_mfma_f32_16x16x32_bf16(af[r], bfr[c], acc[r][c], 0, 0, 0);
    __syncthreads();
  }

  const int cm = m0 + (wave >> 1) * 64 + (lane >> 4) * 4;
  const int cn = n0 + (wave & 1) * 64 + (lane & 15);
#pragma unroll
  for (int c = 0; c < 4; ++c) {
    int gcol = cn + c * 16;
    if (gcol >= N) continue;
    float bv = bias ? bias[gcol] : 0.f;
#pragma unroll
    for (int r = 0; r < 4; ++r) {
#pragma unroll
      for (int i = 0; i < 4; ++i) {
        int grow = cm + r * 16 + i;
        float v = acc[r][c][i] + bv;
        size_t idx = coff + (size_t)grow * ldc + gcol;
        if (MODE == 0) ((float*)Cptr)[idx] = v;
        else if (MODE == 1) ((bf16*)Cptr)[idx] = __float2bfloat16(v);
        else if (MODE == 2) ((float*)Cptr)[idx] = resid[idx] + v;
        else {
          float gl = 0.5f * v * (1.f + erff(v * 0.70710678118654752f));
          ((bf16*)Cptr)[idx] = __float2bfloat16(gl);
        }
      }
    }
  }
}

// ---------------- fused flash attention -------------------------------------
// qkv: [NTOK, 1536] bf16 rows = [q(512) | k(512) | v(512)]
// vT : [16][64][SEQ] bf16 (per b*8+h, head-dim-major V)
// ob : [NTOK, 512] bf16 attention output
// One wave owns a 16-row Q tile of one (b,h); iterates 64-wide KV tiles with
// online softmax. A/B fragments are loaded directly from global (L1/L2-hot);
// only the P (16x64) operand transpose goes through wave-private LDS
// (row stride 72 shorts = 144B -> conflict-free b128 reads). No __syncthreads.
__global__ __launch_bounds__(256) void flash_attn(const bf16* __restrict__ qkv,
                                                  const bf16* __restrict__ vT,
                                                  bf16* __restrict__ ob) {
  const int wave = threadIdx.x >> 6, lane = threadIdx.x & 63;
  const int g  = blockIdx.x * 4 + wave;     // 1024 wave-units
  const int bh = g >> 6;
  const int t6 = g & 63;
  // balanced q-tile assignment: block gets {k, 63-k, k+1, 62-k} -> ~const work
  const int qt = (t6 & 1) ? (63 - (t6 >> 1)) : (t6 >> 1);
  const int b = bh >> 3, h = bh & 7;
  const int ln15 = lane & 15, hi = lane >> 4;
  const int qg0 = qt * 16;                  // first q row (within seq)
  const int nkv = (qt >> 2) + 1;            // # of 64-wide kv tiles (causal)

  __shared__ short smP[4][16 * 72];
  short* Pw = smP[wave];

  // Q fragments resident in registers for the whole kv loop
  const bf16* qbase = qkv + (size_t)(b * SEQ + qg0 + ln15) * 1536 + h * 64 + hi * 8;
  bf16x8 qf[2];
  qf[0] = *(const bf16x8*)(qbase);
  qf[1] = *(const bf16x8*)(qbase + 32);

  const bf16* kbase = qkv + (size_t)(b * SEQ) * 1536 + 512 + h * 64
                      + (size_t)ln15 * 1536 + hi * 8;
  const bf16* vbase = vT + (size_t)bh * 64 * SEQ + (size_t)ln15 * SEQ + hi * 8;

  float m[4], l[4];
  f32x4 acco[4];
#pragma unroll
  for (int i = 0; i < 4; ++i) { m[i] = -3.4e38f; l[i] = 0.f; }
#pragma unroll
  for (int nf = 0; nf < 4; ++nf) acco[nf] = (f32x4){0.f, 0.f, 0.f, 0.f};

  for (int jt = 0; jt < nkv; ++jt) {
    const int kv0 = jt * 64;
    // K fragments (B-frag: row = kv, k = head dim)
    bf16x8 kf[4][2];
#pragma unroll
    for (int cf = 0; cf < 4; ++cf) {
      const bf16* kr = kbase + (size_t)(kv0 + cf * 16) * 1536;
      kf[cf][0] = *(const bf16x8*)(kr);
      kf[cf][1] = *(const bf16x8*)(kr + 32);
    }
    // V^T fragments issued early; consumed only after softmax (latency hidden)
    bf16x8 vf[4][2];
#pragma unroll
    for (int nf = 0; nf < 4; ++nf) {
      const bf16* vr = vbase + (size_t)(nf * 16) * SEQ + kv0;
      vf[nf][0] = *(const bf16x8*)(vr);
      vf[nf][1] = *(const bf16x8*)(vr + 32);
    }
    // S = Q @ K^T   (C layout: col = kv = cf*16+ln15, row = hi*4+i)
    f32x4 accs[4];
#pragma unroll
    for (int cf = 0; cf < 4; ++cf) {
      accs[cf] = (f32x4){0.f, 0.f, 0.f, 0.f};
      accs[cf] = __builtin_amdgcn_mfma_f32_16x16x32_bf16(qf[0], kf[cf][0], accs[cf], 0, 0, 0);
      accs[cf] = __builtin_amdgcn_mfma_f32_16x16x32_bf16(qf[1], kf[cf][1], accs[cf], 0, 0, 0);
    }
    // causal mask: only the last tile of this wave can be partial
    if (jt == nkv - 1) {
#pragma unroll
      for (int cf = 0; cf < 4; ++cf)
#pragma unroll
        for (int i = 0; i < 4; ++i)
          if (kv0 + cf * 16 + ln15 > qg0 + hi * 4 + i) accs[cf][i] = -3.4e38f;
    }
    // online softmax: row reduce across the 16 lanes sharing each row
    float mn[4], f[4];
#pragma unroll
    for (int i = 0; i < 4; ++i) {
      float mm = fmaxf(fmaxf(accs[0][i], accs[1][i]), fmaxf(accs[2][i], accs[3][i]));
#pragma unroll
      for (int o = 1; o < 16; o <<= 1) mm = fmaxf(mm, __shfl_xor(mm, o));
      mn[i] = fmaxf(m[i], mm);
      f[i] = expf((m[i] - mn[i]) * 0.125f);
      m[i] = mn[i];
    }
    float rs[4] = {0.f, 0.f, 0.f, 0.f};
#pragma unroll
    for (int cf = 0; cf < 4; ++cf)
#pragma unroll
      for (int i = 0; i < 4; ++i) {
        float p = expf((accs[cf][i] - mn[i]) * 0.125f);   // masked -> exp(-huge)=0
        accs[cf][i] = p;
        rs[i] += p;
      }
#pragma unroll
    for (int i = 0; i < 4; ++i) {
#pragma unroll
      for (int o = 1; o < 16; o <<= 1) rs[i] += __shfl_xor(rs[i], o);
      l[i] = l[i] * f[i] + rs[i];
    }
    // P -> LDS (C layout) then re-read as A fragments (transpose via LDS)
    asm volatile("" ::: "memory");
#pragma unroll
    for (int cf = 0; cf < 4; ++cf)
#pragma unroll
      for (int i = 0; i < 4; ++i) {
        union { bf16 b; short s; } u;
        u.b = __float2bfloat16(accs[cf][i]);
        Pw[(hi * 4 + i) * 72 + cf * 16 + ln15] = u.s;
      }
    asm volatile("" ::: "memory");
    // rescale O by exp(m_old - m_new)
#pragma unroll
    for (int nf = 0; nf < 4; ++nf)
#pragma unroll
      for (int i = 0; i < 4; ++i) acco[nf][i] *= f[i];
    bf16x8 pf[2];
    pf[0] = *(const bf16x8*)(Pw + ln15 * 72 + hi * 8);
    pf[1] = *(const bf16x8*)(Pw + ln15 * 72 + 32 + hi * 8);
    // O += P @ V
#pragma unroll
    for (int nf = 0; nf < 4; ++nf) {
      acco[nf] = __builtin_amdgcn_mfma_f32_16x16x32_bf16(pf[0], vf[nf][0], acco[nf], 0, 0, 0);
      acco[nf] = __builtin_amdgcn_mfma_f32_16x16x32_bf16(pf[1], vf[nf][1], acco[nf], 0, 0, 0);
    }
  }
  // epilogue: O / l
  bf16* orow = ob + (size_t)(b * SEQ + qg0 + hi * 4) * DMODEL + h * 64 + ln15;
#pragma unroll
  for (int i = 0; i < 4; ++i) {
    float r = 1.f / l[i];
#pragma unroll
    for (int nf = 0; nf < 4; ++nf)
      orow[(size_t)i * DMODEL + nf * 16] = __float2bfloat16(acco[nf][i] * r);
  }
}

// ---------------- layernorm: f32 in -> bf16 out, one block per row ---------
__global__ __launch_bounds__(256) void ln_bf16(const float* __restrict__ x,
                                               const float* __restrict__ g,
                                               const float* __restrict__ b,
                                               bf16* __restrict__ out) {
  int row = blockIdx.x, tid = threadIdx.x;
  const float* xr = x + (size_t)row * DMODEL;
  float2 v = *(const float2*)(xr + tid * 2);
  float s = v.x + v.y, q = v.x * v.x + v.y * v.y;
#pragma unroll
  for (int o = 32; o; o >>= 1) { s += __shfl_down(s, o); q += __shfl_down(q, o); }
  __shared__ float ps[4], pq[4];
  int wave = tid >> 6, lane = tid & 63;
  if (!lane) { ps[wave] = s; pq[wave] = q; }
  __syncthreads();
  s = ps[0] + ps[1] + ps[2] + ps[3];
  q = pq[0] + pq[1] + pq[2] + pq[3];
  float mean = s * (1.f / DMODEL);
  float var  = q * (1.f / DMODEL) - mean * mean;
  float rstd = rsqrtf(var + 1e-5f);
  int d = tid * 2;
  out[(size_t)row * DMODEL + d]     = __float2bfloat16((v.x - mean) * rstd * g[d] + b[d]);
  out[(size_t)row * DMODEL + d + 1] = __float2bfloat16((v.y - mean) * rstd * g[d + 1] + b[d + 1]);
}

// ---------------- embedding + positional ----------------------------------
__global__ __launch_bounds__(256) void embed_k(const int* __restrict__ tok,
                                               const float* __restrict__ emb,
                                               const float* __restrict__ pos,
                                               float* __restrict__ x) {
  int t = blockIdx.x, tid = threadIdx.x;
  int s = t & (SEQ - 1);
  int id = tok[t];
  float2 e = *(const float2*)(emb + (size_t)id * DMODEL + tid * 2);
  float2 p = *(const float2*)(pos + (size_t)s * DMODEL + tid * 2);
  float2 o; o.x = e.x + p.x; o.y = e.y + p.y;
  *(float2*)(x + (size_t)t * DMODEL + tid * 2) = o;
}

// ---------------- V transpose: qkv v-seg -> vT[bh][d][j] -------------------
__global__ __launch_bounds__(256) void transpose_v(const bf16* __restrict__ qkv,
                                                   bf16* __restrict__ vT) {
  int bh = blockIdx.x;             // 0..15
  int b = bh >> 3, h = bh & 7;
  int jt = blockIdx.y * 64;        // grid.y = 16
  const bf16* vb = qkv + (size_t)b * SEQ * 1536 + 1024 + h * 64;
  bf16* vo = vT + (size_t)bh * 64 * SEQ + jt;
#pragma unroll
  for (int it = 0; it < 16; ++it) {
    int e = it * 256 + threadIdx.x;
    int j = e & 63, d = e >> 6;
    vo[(size_t)d * SEQ + j] = vb[(size_t)(jt + j) * 1536 + d];
  }
}

// ---------------- f32 -> bf16 convert --------------------------------------
__global__ __launch_bounds__(256) void cvt_bf16(const float* __restrict__ in,
                                                bf16* __restrict__ out, int n) {
  int i = (blockIdx.x * 256 + threadIdx.x) * 4;
  if (i + 3 < n) {
    float4 v = *(const float4*)(in + i);
    out[i]     = __float2bfloat16(v.x);
    out[i + 1] = __float2bfloat16(v.y);
    out[i + 2] = __float2bfloat16(v.z);
    out[i + 3] = __float2bfloat16(v.w);
  } else {
    for (; i < n; ++i) out[i] = __float2bfloat16(in[i]);
  }
}

// ------- QKV weight concat+convert: dst[l][seg*512 + r][c] ------------------
__global__ __launch_bounds__(256) void cvt_qkv(const float* __restrict__ Wq,
                                               const float* __restrict__ Wk,
                                               const float* __restrict__ Wv,
                                               bf16* __restrict__ dst) {
  int l = blockIdx.y, seg = blockIdx.z;
  const float* src = (seg == 0 ? Wq : seg == 1 ? Wk : Wv) + (size_t)l * 262144;
  bf16* d = dst + (size_t)l * 786432 + (size_t)seg * 262144;
  int i = (blockIdx.x * 256 + threadIdx.x) * 4;
  float4 v = *(const float4*)(src + i);
  d[i]     = __float2bfloat16(v.x);
  d[i + 1] = __float2bfloat16(v.y);
  d[i + 2] = __float2bfloat16(v.z);
  d[i + 3] = __float2bfloat16(v.w);
}

// ------- QKV bias concat: out[l][seg*512 + d] -------------------------------
__global__ __launch_bounds__(512) void bias_qkv(const float* __restrict__ bq,
                                                const float* __restrict__ bk,
                                                const float* __restrict__ bv,
                                                float* __restrict__ out) {
  int l = blockIdx.x, seg = blockIdx.y, d = threadIdx.x;
  const float* src = (seg == 0 ? bq : seg == 1 ? bk : bv);
  out[(size_t)l * 1536 + seg * 512 + d] = src[(size_t)l * 512 + d];
}

extern "C" void kernel_launch(void* const* d_in, const int* in_sizes, int n_in,
                              void* d_out, int out_size, void* d_ws, size_t ws_size,
                              hipStream_t stream) {
  const int*   tokens = (const int*)d_in[0];
  const float* emb    = (const float*)d_in[1];
  const float* pos    = (const float*)d_in[2];
  const float* Wq = (const float*)d_in[3];  const float* bq = (const float*)d_in[4];
  const float* Wk = (const float*)d_in[5];  const float* bk = (const float*)d_in[6];
  const float* Wv = (const float*)d_in[7];  const float* bv = (const float*)d_in[8];
  const float* Wo = (const float*)d_in[9];  const float* bo = (const float*)d_in[10];
  const float* ln1g = (const float*)d_in[11]; const float* ln1b = (const float*)d_in[12];
  const float* W1 = (const float*)d_in[13]; const float* b1 = (const float*)d_in[14];
  const float* W2 = (const float*)d_in[15]; const float* b2 = (const float*)d_in[16];
  const float* ln2g = (const float*)d_in[17]; const float* ln2b = (const float*)d_in[18];
  const float* lnfg = (const float*)d_in[19]; const float* lnfb = (const float*)d_in[20];
  const float* Whead = (const float*)d_in[21]; const float* bhead = (const float*)d_in[22];
  float* out = (float*)d_out;

  // ---- workspace carve ----
  char* w = (char*)d_ws;
  auto carve = [&](size_t bytes) -> char* {
    char* p = w; w += (bytes + 255) & ~(size_t)255; return p;
  };
  bf16*  wQKV = (bf16*)carve((size_t)4 * 1536 * 512 * 2);
  bf16*  wWo  = (bf16*)carve((size_t)4 * 512 * 512 * 2);
  bf16*  wW1  = (bf16*)carve((size_t)4 * NDFF * 512 * 2);
  bf16*  wW2  = (bf16*)carve((size_t)4 * NDFF * 512 * 2);
  bf16*  wWh  = (bf16*)carve((size_t)VOCAB * 512 * 2);
  float* bQKV = (float*)carve((size_t)4 * 1536 * 4);
  float* xbuf = (float*)carve((size_t)NTOK * DMODEL * 4);
  bf16*  hb   = (bf16*)carve((size_t)NTOK * DMODEL * 2);
  bf16*  qkvb = (bf16*)carve((size_t)NTOK * 1536 * 2);
  bf16*  vTb  = (bf16*)carve((size_t)16 * 64 * SEQ * 2);
  bf16*  ob   = (bf16*)carve((size_t)NTOK * DMODEL * 2);
  bf16*  h1b  = (bf16*)carve((size_t)NTOK * NDFF * 2);
  (void)ws_size; (void)n_in; (void)in_sizes; (void)out_size;

  auto cvt = [&](const float* src, bf16* dst, int n) {
    cvt_bf16<<<(n / 4 + 255) / 256, 256, 0, stream>>>(src, dst, n);
  };
  cvt_qkv<<<dim3(256, 4, 3), 256, 0, stream>>>(Wq, Wk, Wv, wQKV);
  bias_qkv<<<dim3(4, 3), 512, 0, stream>>>(bq, bk, bv, bQKV);
  cvt(Wo, wWo, 4 * 512 * 512);
  cvt(W1, wW1, 4 * NDFF * 512);
  cvt(W2, wW2, 4 * NDFF * 512);
  cvt(Whead, wWh, VOCAB * 512);

  embed_k<<<NTOK, 256, 0, stream>>>(tokens, emb, pos, xbuf);

  const dim3 g16x4(16, 4, 1);
  for (int l = 0; l < 4; ++l) {
    const bf16* wqkv = wQKV + (size_t)l * 1536 * 512;
    const bf16* wo = wWo + (size_t)l * 512 * 512;
    const bf16* w1 = wW1 + (size_t)l * NDFF * 512;
    const bf16* w2 = wW2 + (size_t)l * NDFF * 512;

    ln_bf16<<<NTOK, 256, 0, stream>>>(xbuf, ln1g + l * 512, ln1b + l * 512, hb);
    // fused QKV projection: qkvb[t] = [q|k|v]
    gemm_nt<1><<<dim3(16, 12, 1), 256, 0, stream>>>(
        hb, 0, 0, 512, wqkv, 0, 0, 512, bQKV + l * 1536,
        qkvb, 0, 0, 1536, nullptr, 1536, 512, 0);
    transpose_v<<<dim3(16, 16), 256, 0, stream>>>(qkvb, vTb);
    flash_attn<<<256, 256, 0, stream>>>(qkvb, vTb, ob);
    gemm_nt<2><<<g16x4, 256, 0, stream>>>(ob, 0, 0, 512, wo, 0, 0, 512, bo + l * 512,
                                          xbuf, 0, 0, 512, xbuf, 512, 512, 0);
    ln_bf16<<<NTOK, 256, 0, stream>>>(xbuf, ln2g + l * 512, ln2b + l * 512, hb);
    gemm_nt<3><<<dim3(16, 16, 1), 256, 0, stream>>>(hb, 0, 0, 512, w1, 0, 0, 512,
                                                    b1 + l * NDFF, h1b, 0, 0, NDFF,
                                                    nullptr, NDFF, 512, 0);
    gemm_nt<2><<<g16x4, 256, 0, stream>>>(h1b, 0, 0, NDFF, w2, 0, 0, NDFF, b2 + l * 512,
                                          xbuf, 0, 0, 512, xbuf, 512, NDFF, 0);
  }

  ln_bf16<<<NTOK, 256, 0, stream>>>(xbuf, lnfg, lnfb, hb);
  gemm_nt<0><<<dim3(16, 393, 1), 256, 0, stream>>>(hb, 0, 0, 512, wWh, 0, 0, 512, bhead,
                                                   out, 0, 0, VOCAB, nullptr, VOCAB, 512, 0);
}